// Round 14
// baseline (72953.796 us; speedup 1.0000x reference)
//
#include <hip/hip_runtime.h>

// ---- geometry ----
#define PLANE28   784                  // 28*28
#define NPLANE28  (16*64*PLANE28)      // 802816  [16,64,28,28]
#define NPLANE56  (16*64*56*56)        // 3211264 [16,64,56,56]
#define C1T_ROWS  61
#define C1T       (C1T_ROWS*37)        // 2257
#define PPLANE    900                  // padded 30*30
#define NPPLANE   (16*64*PPLANE)       // 921600

// FROZEN SEMANTICS (validated rounds 7-11, absmax=0):
//  - conv reductions: per-ic subtotal. sub = fmaf chain over (ky outer, kx inner),
//    OOB as zero-tap fmaf no-op (zero-halo padded layout is bit-identical);
//    acc = acc + sub in ic order.
//  - membrane: m = mem*0.8f; m = m + conv; [m = m + resid;]  (contract OFF)
//  - fc: 8 x 512-term sequential fmaf chains, subtotals added in order; o = acc + b.
//  - pool sums are exact small integers (order-free), divided by 9.0f / 49.0f.

// ---------------- weight transposes (once per launch) -----------------------
// conv1_w [64oc][20ic][7ky][7kx] -> w1t [20ic][7ky][7kx][64oc]
__global__ __launch_bounds__(256) void transpose_w1(const float* __restrict__ w,
                                                    float* __restrict__ wt) {
    int i = blockIdx.x * 256 + threadIdx.x;
    if (i >= 64 * 20 * 49) return;
    int oc = i / 980;
    int r  = i % 980;
    int ic = r / 49;
    int ky = (r % 49) / 7;
    int kx = r % 7;
    wt[((ic * 7 + ky) * 7 + kx) * 64 + oc] = w[i];
}

// blocks_w [8][64oc][64ic][3ky][3kx] -> wt [8][16 ocg][64 ic][9 t9][4 oc]
__global__ __launch_bounds__(256) void transpose_wb4(const float* __restrict__ w,
                                                     float* __restrict__ wt) {
    int i = blockIdx.x * 256 + threadIdx.x;
    if (i >= 8 * 64 * 64 * 9) return;
    int l  = i / 36864;
    int r  = i % 36864;
    int oc = r / 576;
    int r2 = r % 576;
    int ic = r2 / 9;
    int t9 = r2 % 9;                  // ky*3+kx (frozen tap order)
    wt[l * 36864 + (oc >> 2) * 2304 + ic * 36 + t9 * 4 + (oc & 3)] = w[i];
}

// ---------------- conv1 7x7 s2 p3 (20->64) + membrane, de-interleaved LDS ---
// grid (8 = 4 xtiles x 2 yhalves, 8 ocg, 16 n), 256 threads; 8 ocs x 2 rows.
// Tile columns stored permuted: cp(c) = (c>>1) + 19*(c&1)  (evens 0..18, odds 19..36)
// -> compute reads at col 2tx+kx become lane-consecutive: conflict-free.
__global__ __launch_bounds__(256) void conv1_t3(
    const float* __restrict__ x,    // [16,8,20,112,112]
    const float* __restrict__ wt,   // [20][7][7][64]
    float* __restrict__ c_mem,      // [16,64,56,56]
    int t)
{
    __shared__ float tile[C1T];
    const int tid = threadIdx.x;
    const int bx  = blockIdx.x >> 1;     // 0..3 x-tile
    const int yh  = blockIdx.x & 1;      // 0..1 y-half
    const int oc0 = blockIdx.y * 8;
    const int n   = blockIdx.z;
    const int tx  = tid & 15;
    const int ty  = tid >> 4;            // 0..15, active ty<14
    const float* xin = x + ((size_t)(n * 8 + t)) * 20 * 12544;
    const int cbase = 32 * bx - 3;
    const int row0  = 56 * yh - 3;

    float acc[8][2];
#pragma unroll
    for (int o = 0; o < 8; ++o) { acc[o][0] = 0.f; acc[o][1] = 0.f; }

#pragma unroll
    for (int k = 0; k < 9; ++k) {
        int idx = tid + k * 256;
        if (idx < C1T) {
            int r = idx / 37, c = idx - r * 37;
            int ri = row0 + r, ci = cbase + c;
            float v = 0.f;
            if ((unsigned)ri < 112u && (unsigned)ci < 112u) v = xin[ri * 112 + ci];
            int cpos = (c >> 1) + ((c & 1) ? 19 : 0);
            tile[r * 37 + cpos] = v;
        }
    }

    for (int ic = 0; ic < 20; ++ic) {
        __syncthreads();
        float pre[9];
        if (ic + 1 < 20) {
            const float* src = xin + (ic + 1) * 12544;
#pragma unroll
            for (int k = 0; k < 9; ++k) {
                int idx = tid + k * 256;
                float v = 0.f;
                if (idx < C1T) {
                    int r = idx / 37, c = idx - r * 37;
                    int ri = row0 + r, ci = cbase + c;
                    if ((unsigned)ri < 112u && (unsigned)ci < 112u) v = src[ri * 112 + ci];
                }
                pre[k] = v;
            }
        }
        if (ty < 14) {
            float sub[8][2];
#pragma unroll
            for (int o = 0; o < 8; ++o) { sub[o][0] = 0.f; sub[o][1] = 0.f; }
            const float* wic = wt + ic * (49 * 64) + oc0;
#pragma unroll
            for (int ky = 0; ky < 7; ++ky) {     // ky OUTER (frozen order)
#pragma unroll
                for (int kx = 0; kx < 7; ++kx) { // kx INNER
                    const int koff = (kx >> 1) + ((kx & 1) ? 19 : 0);
                    const float* wp = wic + (ky * 7 + kx) * 64;  // uniform -> s_load
                    const float v0 = tile[(4 * ty + 0 + ky) * 37 + tx + koff];
                    const float v1 = tile[(4 * ty + 2 + ky) * 37 + tx + koff];
#pragma unroll
                    for (int o = 0; o < 8; ++o) {
                        const float wv = wp[o];
                        sub[o][0] = fmaf(v0, wv, sub[o][0]);
                        sub[o][1] = fmaf(v1, wv, sub[o][1]);
                    }
                }
            }
#pragma unroll
            for (int o = 0; o < 8; ++o) {
                acc[o][0] = acc[o][0] + sub[o][0];
                acc[o][1] = acc[o][1] + sub[o][1];
            }
        }
        __syncthreads();
        if (ic + 1 < 20) {
#pragma unroll
            for (int k = 0; k < 9; ++k) {
                int idx = tid + k * 256;
                if (idx < C1T) {
                    int r = idx / 37, c = idx - r * 37;
                    int cpos = (c >> 1) + ((c & 1) ? 19 : 0);
                    tile[r * 37 + cpos] = pre[k];
                }
            }
        }
    }

    const int xg = 16 * bx + tx;
    if (ty < 14 && xg < 56) {
#pragma clang fp contract(off)
#pragma unroll
        for (int o = 0; o < 8; ++o) {
#pragma unroll
            for (int d = 0; d < 2; ++d) {
                const int yg = 28 * yh + 2 * ty + d;
                size_t idx = (((size_t)n * 64 + oc0 + o) * 56 + yg) * 56 + xg;
                float m = c_mem[idx] * 0.8f;
                m = m + acc[o][d];
                c_mem[idx] = m;
            }
        }
    }
}

// ---------------- avg_pool + padded-layout write ----------------------------
// cur (normal [16,64,28,28], for block-0 residual) + pcur (padded [16,64,30,30])
__global__ __launch_bounds__(256) void pool1_p2(const float* __restrict__ c_mem,
                                                float* __restrict__ cur,
                                                float* __restrict__ pcur) {
    int i = blockIdx.x * 256 + threadIdx.x;
    if (i >= NPLANE28) return;
    int xx = i % 28, yy = (i / 28) % 28;
    int p  = i / PLANE28;                // n*64+ch
    const float* src = c_mem + (size_t)p * 3136;
    float s = 0.f;
    for (int ky = 0; ky < 3; ++ky) {
        int iy = 2 * yy - 1 + ky;
        if ((unsigned)iy >= 56u) continue;
        for (int kx = 0; kx < 3; ++kx) {
            int ix = 2 * xx - 1 + kx;
            if ((unsigned)ix < 56u)
                s += (src[iy * 56 + ix] > 0.5f) ? 1.f : 0.f;
        }
    }
    float v = s / 9.0f;
    cur[i] = v;
    pcur[(size_t)p * PPLANE + (yy + 1) * 30 + (xx + 1)] = v;
}

// ---------------- block conv 3x3 s1 p1 (64->64), v5: padded, no masks -------
// grid (4 yq, 16 ocg, 16 n) = 1024 blocks (4/CU); block 256 (196 active).
// thread = 1 pixel x 4 ocs; taps = 3 contiguous row-triples from padded input;
// depth-3 software pipeline (4 tap buffers), full unroll (static indices).
#define BC5_LD(S, IC)                                        \
    {                                                        \
        const float* q = p + (size_t)(IC) * PPLANE;          \
        v[S][0] = q[0];  v[S][1] = q[1];  v[S][2] = q[2];    \
        v[S][3] = q[30]; v[S][4] = q[31]; v[S][5] = q[32];   \
        v[S][6] = q[60]; v[S][7] = q[61]; v[S][8] = q[62];   \
    }

template <bool HASRES, bool PADOUT>
__global__ __launch_bounds__(256, 4) void bconv_v5(
    const float* __restrict__ pin,    // padded [16][64][30][30]
    const float* __restrict__ wt,     // [16 ocg][64 ic][9][4] (this layer)
    float* __restrict__ mem,          // normal [16,64,28,28]
    float* __restrict__ sout,         // normal spikes (or unused if !PADOUT... always written when non-null)
    const float* __restrict__ resid,  // normal residual
    float* __restrict__ psout)        // padded spike out
{
    const int tid = threadIdx.x;
    if (tid >= 196) return;           // no barriers; tail waves exit
    const int yq  = blockIdx.x;       // 0..3
    const int ocg = blockIdx.y;       // 0..15
    const int oc0 = ocg * 4;
    const int n   = blockIdx.z;
    const int xx  = tid % 28;
    const int rl  = tid / 28;         // 0..6
    const int yy  = yq * 7 + rl;

    // top-left tap of the 3x3 window in padded coords = (yy, xx)
    const float* p = pin + (size_t)n * 64 * PPLANE + yy * 30 + xx;
    const float* wblk = wt + ocg * 2304;

    float acc[4];
#pragma unroll
    for (int o = 0; o < 4; ++o) acc[o] = 0.f;

    float v[4][9];
    BC5_LD(0, 0)
    BC5_LD(1, 1)
    BC5_LD(2, 2)
#pragma unroll
    for (int ic = 0; ic < 64; ++ic) {
        if (ic + 3 < 64) BC5_LD((ic + 3) & 3, ic + 3)
        const float* wic = wblk + ic * 36;
        float sub[4];
        sub[0] = 0.f; sub[1] = 0.f; sub[2] = 0.f; sub[3] = 0.f;
#pragma unroll
        for (int t9 = 0; t9 < 9; ++t9) {   // ky outer, kx inner (frozen)
            const float* wp = wic + t9 * 4;
            const float tv = v[ic & 3][t9];
#pragma unroll
            for (int o = 0; o < 4; ++o)
                sub[o] = fmaf(tv, wp[o], sub[o]);
        }
#pragma unroll
        for (int o = 0; o < 4; ++o) acc[o] = acc[o] + sub[o];
    }

    {
#pragma clang fp contract(off)
#pragma unroll
        for (int o = 0; o < 4; ++o) {
            size_t idx = (((size_t)n * 64 + oc0 + o) * 28 + yy) * 28 + xx;
            float m = mem[idx] * 0.8f;
            m = m + acc[o];
            if (HASRES) m = m + resid[idx];
            mem[idx] = m;
            float sp = (m > 0.5f) ? 1.f : 0.f;
            if (PADOUT)
                psout[((size_t)n * 64 + oc0 + o) * PPLANE + (yy + 1) * 30 + (xx + 1)] = sp;
            if (sout) sout[idx] = sp;
        }
    }
}

// ---------------- feat = avgpool7x7(concat s2 of blocks 0,2,4,6) ------------
__global__ __launch_bounds__(256) void featpool_k(const float* __restrict__ s2all,
                                                  float* __restrict__ feat) {
    int i = blockIdx.x * 256 + threadIdx.x;
    if (i >= 16 * 4096) return;
    int n = i >> 12;
    int f = i & 4095;
    int c = f >> 4;
    int py = (f >> 2) & 3, px = f & 3;
    int s = c >> 6, cc = c & 63;
    const float* src = s2all + ((size_t)(2 * s) * 16 * 64 + n * 64 + cc) * PLANE28;
    float sum = 0.f;
    for (int dy = 0; dy < 7; ++dy)
        for (int dx = 0; dx < 7; ++dx)
            sum += src[(py * 7 + dy) * 28 + px * 7 + dx];
    feat[i] = sum / 49.0f;
}

// ---------------- FC: 8 lanes per (n,cls), frozen 8x512 chains --------------
__global__ __launch_bounds__(256) void fc_w8(
    const float* __restrict__ feat, const float* __restrict__ w,
    const float* __restrict__ b, float* __restrict__ fc_mem,
    float* __restrict__ out) {
    int gt = blockIdx.x * 256 + threadIdx.x;
    int g  = gt >> 3;
    int j  = gt & 7;
    if (g >= 16 * 101) return;
    int n = g / 101, cls = g % 101;
    const float* fb = feat + (size_t)n * 4096 + j * 512;
    const float* wb = w + (size_t)cls * 4096 + j * 512;
    float sub = 0.f;
    for (int k = 0; k < 512; ++k)
        sub = fmaf(fb[k], wb[k], sub);
    int lane = threadIdx.x & 63;
    int base = lane & ~7;
    float s0 = __shfl(sub, base + 0, 64);
    float s1 = __shfl(sub, base + 1, 64);
    float s2 = __shfl(sub, base + 2, 64);
    float s3 = __shfl(sub, base + 3, 64);
    float s4 = __shfl(sub, base + 4, 64);
    float s5 = __shfl(sub, base + 5, 64);
    float s6 = __shfl(sub, base + 6, 64);
    float s7 = __shfl(sub, base + 7, 64);
    if (j == 0) {
#pragma clang fp contract(off)
        float a = s0;
        a = a + s1; a = a + s2; a = a + s3;
        a = a + s4; a = a + s5; a = a + s6; a = a + s7;
        float o = a + b[cls];
        float m = fc_mem[g] * 0.8f;
        m = m + o;
        fc_mem[g] = m;
        if (m > 0.5f) out[g] += 0.125f;
    }
}

extern "C" void kernel_launch(void* const* d_in, const int* in_sizes, int n_in,
                              void* d_out, int out_size, void* d_ws, size_t ws_size,
                              hipStream_t stream) {
    const float* x   = (const float*)d_in[0];
    const float* w1  = (const float*)d_in[1];
    const float* wb1 = (const float*)d_in[2];
    const float* wb2 = (const float*)d_in[3];
    const float* fcw = (const float*)d_in[4];
    const float* fcb = (const float*)d_in[5];
    float* out = (float*)d_out;

    // ---- workspace (all fp32): zeroed state first, then scratch
    float* fws    = (float*)d_ws;
    float* c_mem  = fws;                         // 3,211,264
    float* b1m    = c_mem + NPLANE56;            // 8*802,816
    float* b2m    = b1m + 8 * NPLANE28;          // 8*802,816
    float* fc_mem = b2m + 8 * NPLANE28;          // 1,616
    float* cur0   = fc_mem + 1616;               // 802,816
    float* feat   = cur0 + NPLANE28;             // 65,536
    float* s2all  = feat + 16 * 4096;            // 8*802,816
    float* w1t    = s2all + 8 * NPLANE28;        // 62,720
    float* wb1t   = w1t + 62720;                 // 294,912
    float* wb2t   = wb1t + 294912;               // 294,912
    float* pb     = wb2t + 294912;               // 921,600 padded ping
    float* ps1    = pb + NPPLANE;                // 921,600 padded s1

    size_t zeroN = (size_t)NPLANE56 + 16 * NPLANE28 + 1616;
    hipMemsetAsync(c_mem, 0, zeroN * sizeof(float), stream);
    hipMemsetAsync(pb, 0, 2 * (size_t)NPPLANE * sizeof(float), stream);  // zero halos
    hipMemsetAsync(d_out, 0, 16 * 101 * sizeof(float), stream);

    transpose_w1<<<(62720 + 255) / 256, 256, 0, stream>>>(w1, w1t);
    transpose_wb4<<<(294912 + 255) / 256, 256, 0, stream>>>(wb1, wb1t);
    transpose_wb4<<<(294912 + 255) / 256, 256, 0, stream>>>(wb2, wb2t);

    for (int t = 0; t < 8; ++t) {
        conv1_t3<<<dim3(8, 8, 16), 256, 0, stream>>>(x, w1t, c_mem, t);
        pool1_p2<<<NPLANE28 / 256, 256, 0, stream>>>(c_mem, cur0, pb);
        for (int i = 0; i < 8; ++i) {
            const float* wA = wb1t + (size_t)i * 36864;
            const float* wB = wb2t + (size_t)i * 36864;
            float* m1 = b1m + (size_t)i * NPLANE28;
            float* m2 = b2m + (size_t)i * NPLANE28;
            float* so = s2all + (size_t)i * NPLANE28;
            const float* binres = (i == 0) ? cur0 : s2all + (size_t)(i - 1) * NPLANE28;
            // A: reads padded pb, writes padded ps1 (no normal out needed)
            bconv_v5<false, true><<<dim3(4, 16, 16), 256, 0, stream>>>(
                pb, wA, m1, nullptr, nullptr, ps1);
            // B: reads padded ps1, residual normal, writes normal so + padded pb
            bconv_v5<true, true><<<dim3(4, 16, 16), 256, 0, stream>>>(
                ps1, wB, m2, so, binres, pb);
        }
        featpool_k<<<16 * 4096 / 256, 256, 0, stream>>>(s2all, feat);
        fc_w8<<<(16 * 101 * 8 + 255) / 256, 256, 0, stream>>>(feat, fcw, fcb, fc_mem, out);
    }
}

// Round 15
// 5182.222 us; speedup vs baseline: 14.0777x; 14.0777x over previous
//
#include <hip/hip_runtime.h>

// ---- geometry ----
#define PLANE28   784                  // 28*28
#define NPLANE28  (16*64*PLANE28)      // 802816  [16,64,28,28]
#define NPLANE56  (16*64*56*56)        // 3211264 [16,64,56,56]
#define C1T_ROWS  61
#define C1T       (C1T_ROWS*37)        // 2257
#define PPLANE    900                  // padded 30*30
#define NPPLANE   (16*64*PPLANE)       // 921600

// FROZEN SEMANTICS (validated rounds 7-11, absmax=0):
//  - conv reductions: per-ic subtotal. sub = fmaf chain over (ky outer, kx inner),
//    OOB as zero-tap fmaf no-op (zero-halo padded layout is bit-identical);
//    acc = acc + sub in ic order.
//  - membrane: m = mem*0.8f; m = m + conv; [m = m + resid;]  (contract OFF)
//  - fc: 8 x 512-term sequential fmaf chains, subtotals added in order; o = acc + b.
//  - pool sums are exact small integers (order-free), divided by 9.0f / 49.0f.
// LESSON (round 14): never fully unroll a software-pipelined load loop — the
// compiler hoists all loads and spills to scratch (812MB/dispatch HBM). Use
// named ring buffers + unroll(disable).

// ---------------- weight transposes (once per launch) -----------------------
__global__ __launch_bounds__(256) void transpose_w1(const float* __restrict__ w,
                                                    float* __restrict__ wt) {
    int i = blockIdx.x * 256 + threadIdx.x;
    if (i >= 64 * 20 * 49) return;
    int oc = i / 980;
    int r  = i % 980;
    int ic = r / 49;
    int ky = (r % 49) / 7;
    int kx = r % 7;
    wt[((ic * 7 + ky) * 7 + kx) * 64 + oc] = w[i];
}

// blocks_w [8][64oc][64ic][3ky][3kx] -> wt [8][16 ocg][64 ic][9 t9][4 oc]
__global__ __launch_bounds__(256) void transpose_wb4(const float* __restrict__ w,
                                                     float* __restrict__ wt) {
    int i = blockIdx.x * 256 + threadIdx.x;
    if (i >= 8 * 64 * 64 * 9) return;
    int l  = i / 36864;
    int r  = i % 36864;
    int oc = r / 576;
    int r2 = r % 576;
    int ic = r2 / 9;
    int t9 = r2 % 9;                  // ky*3+kx (frozen tap order)
    wt[l * 36864 + (oc >> 2) * 2304 + ic * 36 + t9 * 4 + (oc & 3)] = w[i];
}

// ---------------- conv1 7x7 s2 p3 (20->64) + membrane, de-interleaved LDS ---
// (round 14 version — passed; columns permuted for conflict-free reads)
__global__ __launch_bounds__(256) void conv1_t3(
    const float* __restrict__ x,    // [16,8,20,112,112]
    const float* __restrict__ wt,   // [20][7][7][64]
    float* __restrict__ c_mem,      // [16,64,56,56]
    int t)
{
    __shared__ float tile[C1T];
    const int tid = threadIdx.x;
    const int bx  = blockIdx.x >> 1;
    const int yh  = blockIdx.x & 1;
    const int oc0 = blockIdx.y * 8;
    const int n   = blockIdx.z;
    const int tx  = tid & 15;
    const int ty  = tid >> 4;            // active ty<14
    const float* xin = x + ((size_t)(n * 8 + t)) * 20 * 12544;
    const int cbase = 32 * bx - 3;
    const int row0  = 56 * yh - 3;

    float acc[8][2];
#pragma unroll
    for (int o = 0; o < 8; ++o) { acc[o][0] = 0.f; acc[o][1] = 0.f; }

#pragma unroll
    for (int k = 0; k < 9; ++k) {
        int idx = tid + k * 256;
        if (idx < C1T) {
            int r = idx / 37, c = idx - r * 37;
            int ri = row0 + r, ci = cbase + c;
            float v = 0.f;
            if ((unsigned)ri < 112u && (unsigned)ci < 112u) v = xin[ri * 112 + ci];
            int cpos = (c >> 1) + ((c & 1) ? 19 : 0);
            tile[r * 37 + cpos] = v;
        }
    }

    for (int ic = 0; ic < 20; ++ic) {
        __syncthreads();
        float pre[9];
        if (ic + 1 < 20) {
            const float* src = xin + (ic + 1) * 12544;
#pragma unroll
            for (int k = 0; k < 9; ++k) {
                int idx = tid + k * 256;
                float v = 0.f;
                if (idx < C1T) {
                    int r = idx / 37, c = idx - r * 37;
                    int ri = row0 + r, ci = cbase + c;
                    if ((unsigned)ri < 112u && (unsigned)ci < 112u) v = src[ri * 112 + ci];
                }
                pre[k] = v;
            }
        }
        if (ty < 14) {
            float sub[8][2];
#pragma unroll
            for (int o = 0; o < 8; ++o) { sub[o][0] = 0.f; sub[o][1] = 0.f; }
            const float* wic = wt + ic * (49 * 64) + oc0;
#pragma unroll
            for (int ky = 0; ky < 7; ++ky) {     // ky OUTER (frozen order)
#pragma unroll
                for (int kx = 0; kx < 7; ++kx) { // kx INNER
                    const int koff = (kx >> 1) + ((kx & 1) ? 19 : 0);
                    const float* wp = wic + (ky * 7 + kx) * 64;  // uniform -> s_load
                    const float v0 = tile[(4 * ty + 0 + ky) * 37 + tx + koff];
                    const float v1 = tile[(4 * ty + 2 + ky) * 37 + tx + koff];
#pragma unroll
                    for (int o = 0; o < 8; ++o) {
                        const float wv = wp[o];
                        sub[o][0] = fmaf(v0, wv, sub[o][0]);
                        sub[o][1] = fmaf(v1, wv, sub[o][1]);
                    }
                }
            }
#pragma unroll
            for (int o = 0; o < 8; ++o) {
                acc[o][0] = acc[o][0] + sub[o][0];
                acc[o][1] = acc[o][1] + sub[o][1];
            }
        }
        __syncthreads();
        if (ic + 1 < 20) {
#pragma unroll
            for (int k = 0; k < 9; ++k) {
                int idx = tid + k * 256;
                if (idx < C1T) {
                    int r = idx / 37, c = idx - r * 37;
                    int cpos = (c >> 1) + ((c & 1) ? 19 : 0);
                    tile[r * 37 + cpos] = pre[k];
                }
            }
        }
    }

    const int xg = 16 * bx + tx;
    if (ty < 14 && xg < 56) {
#pragma clang fp contract(off)
#pragma unroll
        for (int o = 0; o < 8; ++o) {
#pragma unroll
            for (int d = 0; d < 2; ++d) {
                const int yg = 28 * yh + 2 * ty + d;
                size_t idx = (((size_t)n * 64 + oc0 + o) * 56 + yg) * 56 + xg;
                float m = c_mem[idx] * 0.8f;
                m = m + acc[o][d];
                c_mem[idx] = m;
            }
        }
    }
}

// ---------------- avg_pool + padded-layout write ----------------------------
__global__ __launch_bounds__(256) void pool1_p2(const float* __restrict__ c_mem,
                                                float* __restrict__ cur,
                                                float* __restrict__ pcur) {
    int i = blockIdx.x * 256 + threadIdx.x;
    if (i >= NPLANE28) return;
    int xx = i % 28, yy = (i / 28) % 28;
    int p  = i / PLANE28;
    const float* src = c_mem + (size_t)p * 3136;
    float s = 0.f;
    for (int ky = 0; ky < 3; ++ky) {
        int iy = 2 * yy - 1 + ky;
        if ((unsigned)iy >= 56u) continue;
        for (int kx = 0; kx < 3; ++kx) {
            int ix = 2 * xx - 1 + kx;
            if ((unsigned)ix < 56u)
                s += (src[iy * 56 + ix] > 0.5f) ? 1.f : 0.f;
        }
    }
    float v = s / 9.0f;
    cur[i] = v;
    pcur[(size_t)p * PPLANE + (yy + 1) * 30 + (xx + 1)] = v;
}

// ---------------- block conv 3x3 s1 p1 (64->64), v6 -------------------------
// Padded input (no masks) + v4's proven rolling structure, pipeline depth 2
// blocks via 4 NAMED ring buffers in a NON-unrolled loop (16 iters x 4 ic).
#define BC6_LD(V, IC)                                        \
    {                                                        \
        const float* q = p + (size_t)(IC) * PPLANE;          \
        V[0] = q[0];  V[1] = q[1];  V[2] = q[2];             \
        V[3] = q[30]; V[4] = q[31]; V[5] = q[32];            \
        V[6] = q[60]; V[7] = q[61]; V[8] = q[62];            \
    }

#define BC6_COMP(V, IC)                                      \
    {                                                        \
        const float* wic = wblk + (IC) * 36;                 \
        float sub[4];                                        \
        sub[0] = 0.f; sub[1] = 0.f; sub[2] = 0.f; sub[3] = 0.f; \
        _Pragma("unroll")                                    \
        for (int t9 = 0; t9 < 9; ++t9) {   /* ky outer, kx inner (frozen) */ \
            const float* wp = wic + t9 * 4;                  \
            _Pragma("unroll")                                \
            for (int o = 0; o < 4; ++o)                      \
                sub[o] = fmaf(V[t9], wp[o], sub[o]);         \
        }                                                    \
        _Pragma("unroll")                                    \
        for (int o = 0; o < 4; ++o) acc[o] = acc[o] + sub[o];\
    }

template <bool HASRES, bool WRITESOUT>
__global__ __launch_bounds__(256, 4) void bconv_v6(
    const float* __restrict__ pin,    // padded [16][64][30][30]
    const float* __restrict__ wt,     // [16 ocg][64 ic][9][4] (this layer)
    float* __restrict__ mem,          // normal [16,64,28,28]
    float* __restrict__ sout,         // normal spikes (used iff WRITESOUT)
    const float* __restrict__ resid,  // normal residual (used iff HASRES)
    float* __restrict__ psout)        // padded spike out (always written)
{
    const int tid = threadIdx.x;
    if (tid >= 196) return;           // no barriers; tail waves exit
    const int yq  = blockIdx.x;       // 0..3
    const int ocg = blockIdx.y;       // 0..15
    const int oc0 = ocg * 4;
    const int n   = blockIdx.z;
    const int xx  = tid % 28;
    const int rl  = tid / 28;         // 0..6
    const int yy  = yq * 7 + rl;

    const float* p = pin + (size_t)n * 64 * PPLANE + yy * 30 + xx;
    const float* wblk = wt + ocg * 2304;

    float acc[4];
#pragma unroll
    for (int o = 0; o < 4; ++o) acc[o] = 0.f;

    float va[9], vb[9], vc[9], vd[9];
    BC6_LD(va, 0)
    BC6_LD(vb, 1)
#pragma clang loop unroll(disable)
    for (int ic = 0; ic < 64; ic += 4) {
        BC6_LD(vc, ic + 2)
        BC6_COMP(va, ic)
        BC6_LD(vd, ic + 3)
        BC6_COMP(vb, ic + 1)
        if (ic + 4 < 64) BC6_LD(va, ic + 4)
        BC6_COMP(vc, ic + 2)
        if (ic + 5 < 64) BC6_LD(vb, ic + 5)
        BC6_COMP(vd, ic + 3)
    }

    {
#pragma clang fp contract(off)
#pragma unroll
        for (int o = 0; o < 4; ++o) {
            size_t idx = (((size_t)n * 64 + oc0 + o) * 28 + yy) * 28 + xx;
            float m = mem[idx] * 0.8f;
            m = m + acc[o];
            if (HASRES) m = m + resid[idx];
            mem[idx] = m;
            float sp = (m > 0.5f) ? 1.f : 0.f;
            psout[((size_t)n * 64 + oc0 + o) * PPLANE + (yy + 1) * 30 + (xx + 1)] = sp;
            if (WRITESOUT) sout[idx] = sp;
        }
    }
}

// ---------------- feat = avgpool7x7(concat s2 of blocks 0,2,4,6) ------------
__global__ __launch_bounds__(256) void featpool_k(const float* __restrict__ s2all,
                                                  float* __restrict__ feat) {
    int i = blockIdx.x * 256 + threadIdx.x;
    if (i >= 16 * 4096) return;
    int n = i >> 12;
    int f = i & 4095;
    int c = f >> 4;
    int py = (f >> 2) & 3, px = f & 3;
    int s = c >> 6, cc = c & 63;
    const float* src = s2all + ((size_t)(2 * s) * 16 * 64 + n * 64 + cc) * PLANE28;
    float sum = 0.f;
    for (int dy = 0; dy < 7; ++dy)
        for (int dx = 0; dx < 7; ++dx)
            sum += src[(py * 7 + dy) * 28 + px * 7 + dx];
    feat[i] = sum / 49.0f;
}

// ---------------- FC: 8 lanes per (n,cls), frozen 8x512 chains --------------
__global__ __launch_bounds__(256) void fc_w8(
    const float* __restrict__ feat, const float* __restrict__ w,
    const float* __restrict__ b, float* __restrict__ fc_mem,
    float* __restrict__ out) {
    int gt = blockIdx.x * 256 + threadIdx.x;
    int g  = gt >> 3;
    int j  = gt & 7;
    if (g >= 16 * 101) return;
    int n = g / 101, cls = g % 101;
    const float* fb = feat + (size_t)n * 4096 + j * 512;
    const float* wb = w + (size_t)cls * 4096 + j * 512;
    float sub = 0.f;
    for (int k = 0; k < 512; ++k)
        sub = fmaf(fb[k], wb[k], sub);
    int lane = threadIdx.x & 63;
    int base = lane & ~7;
    float s0 = __shfl(sub, base + 0, 64);
    float s1 = __shfl(sub, base + 1, 64);
    float s2 = __shfl(sub, base + 2, 64);
    float s3 = __shfl(sub, base + 3, 64);
    float s4 = __shfl(sub, base + 4, 64);
    float s5 = __shfl(sub, base + 5, 64);
    float s6 = __shfl(sub, base + 6, 64);
    float s7 = __shfl(sub, base + 7, 64);
    if (j == 0) {
#pragma clang fp contract(off)
        float a = s0;
        a = a + s1; a = a + s2; a = a + s3;
        a = a + s4; a = a + s5; a = a + s6; a = a + s7;
        float o = a + b[cls];
        float m = fc_mem[g] * 0.8f;
        m = m + o;
        fc_mem[g] = m;
        if (m > 0.5f) out[g] += 0.125f;
    }
}

extern "C" void kernel_launch(void* const* d_in, const int* in_sizes, int n_in,
                              void* d_out, int out_size, void* d_ws, size_t ws_size,
                              hipStream_t stream) {
    const float* x   = (const float*)d_in[0];
    const float* w1  = (const float*)d_in[1];
    const float* wb1 = (const float*)d_in[2];
    const float* wb2 = (const float*)d_in[3];
    const float* fcw = (const float*)d_in[4];
    const float* fcb = (const float*)d_in[5];
    float* out = (float*)d_out;

    // ---- workspace (all fp32): zeroed state first, then scratch
    float* fws    = (float*)d_ws;
    float* c_mem  = fws;                         // 3,211,264
    float* b1m    = c_mem + NPLANE56;            // 8*802,816
    float* b2m    = b1m + 8 * NPLANE28;          // 8*802,816
    float* fc_mem = b2m + 8 * NPLANE28;          // 1,616
    float* cur0   = fc_mem + 1616;               // 802,816
    float* feat   = cur0 + NPLANE28;             // 65,536
    float* s2all  = feat + 16 * 4096;            // 8*802,816
    float* w1t    = s2all + 8 * NPLANE28;        // 62,720
    float* wb1t   = w1t + 62720;                 // 294,912
    float* wb2t   = wb1t + 294912;               // 294,912
    float* pb     = wb2t + 294912;               // 921,600 padded ping
    float* ps1    = pb + NPPLANE;                // 921,600 padded s1

    size_t zeroN = (size_t)NPLANE56 + 16 * NPLANE28 + 1616;
    hipMemsetAsync(c_mem, 0, zeroN * sizeof(float), stream);
    hipMemsetAsync(pb, 0, 2 * (size_t)NPPLANE * sizeof(float), stream);  // zero halos
    hipMemsetAsync(d_out, 0, 16 * 101 * sizeof(float), stream);

    transpose_w1<<<(62720 + 255) / 256, 256, 0, stream>>>(w1, w1t);
    transpose_wb4<<<(294912 + 255) / 256, 256, 0, stream>>>(wb1, wb1t);
    transpose_wb4<<<(294912 + 255) / 256, 256, 0, stream>>>(wb2, wb2t);

    for (int t = 0; t < 8; ++t) {
        conv1_t3<<<dim3(8, 8, 16), 256, 0, stream>>>(x, w1t, c_mem, t);
        pool1_p2<<<NPLANE28 / 256, 256, 0, stream>>>(c_mem, cur0, pb);
        for (int i = 0; i < 8; ++i) {
            const float* wA = wb1t + (size_t)i * 36864;
            const float* wB = wb2t + (size_t)i * 36864;
            float* m1 = b1m + (size_t)i * NPLANE28;
            float* m2 = b2m + (size_t)i * NPLANE28;
            float* so = s2all + (size_t)i * NPLANE28;
            const float* binres = (i == 0) ? cur0 : s2all + (size_t)(i - 1) * NPLANE28;
            // A: reads padded pb, writes padded ps1
            bconv_v6<false, false><<<dim3(4, 16, 16), 256, 0, stream>>>(
                pb, wA, m1, nullptr, nullptr, ps1);
            // B: reads padded ps1, residual normal, writes normal so + padded pb
            bconv_v6<true, true><<<dim3(4, 16, 16), 256, 0, stream>>>(
                ps1, wB, m2, so, binres, pb);
        }
        featpool_k<<<16 * 4096 / 256, 256, 0, stream>>>(s2all, feat);
        fc_w8<<<(16 * 101 * 8 + 255) / 256, 256, 0, stream>>>(feat, fcw, fcb, fc_mem, out);
    }
}